// Round 1
// baseline (231.588 us; speedup 1.0000x reference)
//
#include <hip/hip_runtime.h>
#include <hip/hip_bf16.h>
#include <math.h>

// Problem constants (from reference setup_inputs)
#define B_DIM 16
#define P_DIM 64
#define L_DIM 9

// ---------------------------------------------------------------------------
// Kernel 1: transpose x (B, N, P) f32  ->  xt (N, P, B) f32
// One thread handles (n, q) where q indexes a quad of p (p = 4q..4q+3).
// Reads: 16 coalesced float4 loads (one per b). Writes: 256 B contiguous.
// ---------------------------------------------------------------------------
__global__ __launch_bounds__(256) void transpose_bnp_to_npb(
    const float* __restrict__ x, float* __restrict__ xt, int N) {
    int t = blockIdx.x * 256 + threadIdx.x;   // over N * 16
    int n = t >> 4;
    int q = t & 15;                            // p-quad: p = 4q .. 4q+3
    if (n >= N) return;

    float v[16][4];
    #pragma unroll
    for (int b = 0; b < 16; ++b) {
        float4 r = *(const float4*)(x + (size_t)b * N * P_DIM
                                      + (size_t)n * P_DIM + 4 * q);
        v[b][0] = r.x; v[b][1] = r.y; v[b][2] = r.z; v[b][3] = r.w;
    }

    // xt[n, p, b] linear offset = (n*64 + p)*16 + b
    float4* dst = (float4*)(xt + ((size_t)n * P_DIM + 4 * q) * B_DIM);
    #pragma unroll
    for (int pp = 0; pp < 4; ++pp) {
        #pragma unroll
        for (int j = 0; j < 4; ++j) {
            float4 w;
            w.x = v[4 * j + 0][pp];
            w.y = v[4 * j + 1][pp];
            w.z = v[4 * j + 2][pp];
            w.w = v[4 * j + 3][pp];
            dst[4 * pp + j] = w;
        }
    }
}

// ---------------------------------------------------------------------------
// Kernel 2: gather + max from xt (N, P, B).
// One thread per (m, p): reads 9 indices once (shared by all 16 batches),
// fetches 9 full 64 B lines, keeps 16 running maxes in registers.
// ---------------------------------------------------------------------------
__global__ __launch_bounds__(256) void gather_max_npb(
    const float* __restrict__ xt, const int* __restrict__ lrf,
    float* __restrict__ out, int M, int N) {
    int t = blockIdx.x * 256 + threadIdx.x;   // over M * 64
    int m = t >> 6;
    int p = t & 63;
    if (m >= M) return;

    const int* ip = lrf + ((size_t)m * P_DIM + p) * L_DIM;
    int idx[L_DIM];
    #pragma unroll
    for (int l = 0; l < L_DIM; ++l) idx[l] = ip[l];

    float mx[16];
    #pragma unroll
    for (int b = 0; b < 16; ++b) mx[b] = -INFINITY;

    #pragma unroll
    for (int l = 0; l < L_DIM; ++l) {
        const float4* src = (const float4*)(xt + ((size_t)idx[l] * P_DIM + p) * B_DIM);
        #pragma unroll
        for (int j = 0; j < 4; ++j) {
            float4 r = src[j];
            mx[4 * j + 0] = fmaxf(mx[4 * j + 0], r.x);
            mx[4 * j + 1] = fmaxf(mx[4 * j + 1], r.y);
            mx[4 * j + 2] = fmaxf(mx[4 * j + 2], r.z);
            mx[4 * j + 3] = fmaxf(mx[4 * j + 3], r.w);
        }
    }

    // out[b, m, p] = mx[b]; consecutive lanes (p) -> coalesced per b
    #pragma unroll
    for (int b = 0; b < 16; ++b)
        out[(size_t)b * M * P_DIM + (size_t)m * P_DIM + p] = mx[b];
}

// ---------------------------------------------------------------------------
// Fallback: direct gather from x (B, N, P) if workspace is too small.
// ---------------------------------------------------------------------------
__global__ __launch_bounds__(256) void gather_max_direct(
    const float* __restrict__ x, const int* __restrict__ lrf,
    float* __restrict__ out, int M, int N) {
    int t = blockIdx.x * 256 + threadIdx.x;
    int m = t >> 6;
    int p = t & 63;
    if (m >= M) return;

    const int* ip = lrf + ((size_t)m * P_DIM + p) * L_DIM;
    int idx[L_DIM];
    #pragma unroll
    for (int l = 0; l < L_DIM; ++l) idx[l] = ip[l];

    float mx[16];
    #pragma unroll
    for (int b = 0; b < 16; ++b) mx[b] = -INFINITY;

    #pragma unroll
    for (int l = 0; l < L_DIM; ++l) {
        const float* col = x + (size_t)idx[l] * P_DIM + p;
        #pragma unroll
        for (int b = 0; b < 16; ++b)
            mx[b] = fmaxf(mx[b], col[(size_t)b * N * P_DIM]);
    }

    #pragma unroll
    for (int b = 0; b < 16; ++b)
        out[(size_t)b * M * P_DIM + (size_t)m * P_DIM + p] = mx[b];
}

extern "C" void kernel_launch(void* const* d_in, const int* in_sizes, int n_in,
                              void* d_out, int out_size, void* d_ws, size_t ws_size,
                              hipStream_t stream) {
    const float* x   = (const float*)d_in[0];
    const int*   lrf = (const int*)d_in[1];
    float*       out = (float*)d_out;

    const int N = in_sizes[0] / (B_DIM * P_DIM);   // 65536
    const int M = in_sizes[1] / (P_DIM * L_DIM);   // 4096

    const size_t xt_bytes = (size_t)N * P_DIM * B_DIM * sizeof(float); // 256 MiB

    if (ws_size >= xt_bytes) {
        float* xt = (float*)d_ws;
        {
            int threads = N * 16;
            int blocks = (threads + 255) / 256;
            transpose_bnp_to_npb<<<blocks, 256, 0, stream>>>(x, xt, N);
        }
        {
            int threads = M * P_DIM;
            int blocks = (threads + 255) / 256;
            gather_max_npb<<<blocks, 256, 0, stream>>>(xt, lrf, out, M, N);
        }
    } else {
        int threads = M * P_DIM;
        int blocks = (threads + 255) / 256;
        gather_max_direct<<<blocks, 256, 0, stream>>>(x, lrf, out, M, N);
    }
}

// Round 2
// 120.158 us; speedup vs baseline: 1.9274x; 1.9274x over previous
//
#include <hip/hip_runtime.h>
#include <hip/hip_bf16.h>
#include <math.h>

// Problem constants (from reference setup_inputs)
#define B_DIM 16
#define P_DIM 64
#define L_DIM 9

__device__ __forceinline__ unsigned int pack2_bf16(float a, float b) {
    __hip_bfloat16 ba = __float2bfloat16(a);   // RNE
    __hip_bfloat16 bb = __float2bfloat16(b);
    unsigned short ua = *(const unsigned short*)&ba;
    unsigned short ub = *(const unsigned short*)&bb;
    return (unsigned int)ua | ((unsigned int)ub << 16);
}

// ---------------------------------------------------------------------------
// Kernel 1: transpose + pack  x (B,N,P) f32  ->  xt (N,P,B) bf16
// Thread t: h = t&1 selects b-half (b = 8h..8h+7), np = t>>1 is (n*64+p).
//   Loads : 8 scalar f32; per instruction a wave reads two dense 128 B
//           segments (h=0 stream and h=1 stream) — full line utilization.
//   Store : one uint4 at byte addr t*16 — perfectly dense across lanes.
// ~20 VGPRs live, no spill (round-1 version spilled with v[16][4]).
// ---------------------------------------------------------------------------
__global__ __launch_bounds__(256) void transpose_pack_bf16(
    const float* __restrict__ x, unsigned short* __restrict__ xt, int N) {
    int t = blockIdx.x * 256 + threadIdx.x;     // over N*P*2
    int h  = t & 1;                             // b-half
    int np = t >> 1;                            // n*64 + p
    if (np >= N * P_DIM) return;

    const float* base = x + (size_t)(8 * h) * N * P_DIM + np;
    const size_t bs = (size_t)N * P_DIM;        // stride between b planes

    float v[8];
    #pragma unroll
    for (int j = 0; j < 8; ++j)
        v[j] = __builtin_nontemporal_load(base + (size_t)j * bs);

    uint4 w;
    w.x = pack2_bf16(v[0], v[1]);
    w.y = pack2_bf16(v[2], v[3]);
    w.z = pack2_bf16(v[4], v[5]);
    w.w = pack2_bf16(v[6], v[7]);

    // xt element offset: np*16 + 8h  ->  ushort index t*8 (16 B per thread)
    *(uint4*)(xt + (size_t)t * 8) = w;
}

// ---------------------------------------------------------------------------
// Kernel 2: gather + max from xt (N,P,B) bf16.
// One thread per (m,p): 9 indices shared by all 16 batches; each gather is
// one 32 B region (two dwordx4 loads). xt = 128 MiB -> mostly L3-resident.
// ---------------------------------------------------------------------------
__global__ __launch_bounds__(256) void gather_max_bf16(
    const unsigned short* __restrict__ xt, const int* __restrict__ lrf,
    float* __restrict__ out, int M, int N) {
    int t = blockIdx.x * 256 + threadIdx.x;     // over M*64
    int m = t >> 6;
    int p = t & 63;
    if (m >= M) return;

    const int* ip = lrf + ((size_t)m * P_DIM + p) * L_DIM;
    int idx[L_DIM];
    #pragma unroll
    for (int l = 0; l < L_DIM; ++l) idx[l] = ip[l];

    float mx[16];
    #pragma unroll
    for (int b = 0; b < 16; ++b) mx[b] = -INFINITY;

    #pragma unroll
    for (int l = 0; l < L_DIM; ++l) {
        const uint4* src = (const uint4*)(xt + ((size_t)idx[l] * P_DIM + p) * B_DIM);
        uint4 a = src[0];
        uint4 c = src[1];
        unsigned int w[8] = {a.x, a.y, a.z, a.w, c.x, c.y, c.z, c.w};
        #pragma unroll
        for (int k = 0; k < 8; ++k) {
            float flo = __uint_as_float(w[k] << 16);          // low bf16 -> f32 (exact)
            float fhi = __uint_as_float(w[k] & 0xFFFF0000u);  // high bf16 -> f32 (exact)
            mx[2 * k]     = fmaxf(mx[2 * k],     flo);
            mx[2 * k + 1] = fmaxf(mx[2 * k + 1], fhi);
        }
    }

    #pragma unroll
    for (int b = 0; b < 16; ++b)
        out[(size_t)b * M * P_DIM + (size_t)m * P_DIM + p] = mx[b];
}

// ---------------------------------------------------------------------------
// Fallback: direct gather from x (B,N,P) f32 if workspace is too small.
// ---------------------------------------------------------------------------
__global__ __launch_bounds__(256) void gather_max_direct(
    const float* __restrict__ x, const int* __restrict__ lrf,
    float* __restrict__ out, int M, int N) {
    int t = blockIdx.x * 256 + threadIdx.x;
    int m = t >> 6;
    int p = t & 63;
    if (m >= M) return;

    const int* ip = lrf + ((size_t)m * P_DIM + p) * L_DIM;
    int idx[L_DIM];
    #pragma unroll
    for (int l = 0; l < L_DIM; ++l) idx[l] = ip[l];

    float mx[16];
    #pragma unroll
    for (int b = 0; b < 16; ++b) mx[b] = -INFINITY;

    #pragma unroll
    for (int l = 0; l < L_DIM; ++l) {
        const float* col = x + (size_t)idx[l] * P_DIM + p;
        #pragma unroll
        for (int b = 0; b < 16; ++b)
            mx[b] = fmaxf(mx[b], col[(size_t)b * N * P_DIM]);
    }

    #pragma unroll
    for (int b = 0; b < 16; ++b)
        out[(size_t)b * M * P_DIM + (size_t)m * P_DIM + p] = mx[b];
}

extern "C" void kernel_launch(void* const* d_in, const int* in_sizes, int n_in,
                              void* d_out, int out_size, void* d_ws, size_t ws_size,
                              hipStream_t stream) {
    const float* x   = (const float*)d_in[0];
    const int*   lrf = (const int*)d_in[1];
    float*       out = (float*)d_out;

    const int N = in_sizes[0] / (B_DIM * P_DIM);   // 65536
    const int M = in_sizes[1] / (P_DIM * L_DIM);   // 4096

    const size_t xt_bytes = (size_t)N * P_DIM * B_DIM * sizeof(unsigned short); // 128 MiB

    if (ws_size >= xt_bytes) {
        unsigned short* xt = (unsigned short*)d_ws;
        {
            int threads = N * P_DIM * 2;           // 8.4M
            int blocks = (threads + 255) / 256;    // 32768
            transpose_pack_bf16<<<blocks, 256, 0, stream>>>(x, xt, N);
        }
        {
            int threads = M * P_DIM;               // 256K
            int blocks = (threads + 255) / 256;    // 1024
            gather_max_bf16<<<blocks, 256, 0, stream>>>(xt, lrf, out, M, N);
        }
    } else {
        int threads = M * P_DIM;
        int blocks = (threads + 255) / 256;
        gather_max_direct<<<blocks, 256, 0, stream>>>(x, lrf, out, M, N);
    }
}

// Round 3
// 118.702 us; speedup vs baseline: 1.9510x; 1.0123x over previous
//
#include <hip/hip_runtime.h>
#include <hip/hip_bf16.h>
#include <math.h>

// Problem constants (from reference setup_inputs)
#define B_DIM 16
#define P_DIM 64
#define L_DIM 9

__device__ __forceinline__ unsigned int pack2_bf16(float a, float b) {
    __hip_bfloat16 ba = __float2bfloat16(a);   // RNE
    __hip_bfloat16 bb = __float2bfloat16(b);
    unsigned short ua = *(const unsigned short*)&ba;
    unsigned short ub = *(const unsigned short*)&bb;
    return (unsigned int)ua | ((unsigned int)ub << 16);
}

// ---------------------------------------------------------------------------
// Kernel 1: transpose + pack  x (B,N,P) f32  ->  xt (N,P,B) bf16
// Thread t: h = t&1 selects b-half (b = 8h..8h+7), np = t>>1 is (n*64+p).
//   Loads : 8 scalar f32; per instruction a wave reads two dense 128 B
//           segments. Store: one uint4 at byte addr t*16 — dense across lanes.
// ---------------------------------------------------------------------------
__global__ __launch_bounds__(256) void transpose_pack_bf16(
    const float* __restrict__ x, unsigned short* __restrict__ xt, int N) {
    int t = blockIdx.x * 256 + threadIdx.x;     // over N*P*2
    int h  = t & 1;                             // b-half
    int np = t >> 1;                            // n*64 + p
    if (np >= N * P_DIM) return;

    const float* base = x + (size_t)(8 * h) * N * P_DIM + np;
    const size_t bs = (size_t)N * P_DIM;        // stride between b planes

    float v[8];
    #pragma unroll
    for (int j = 0; j < 8; ++j)
        v[j] = __builtin_nontemporal_load(base + (size_t)j * bs);

    uint4 w;
    w.x = pack2_bf16(v[0], v[1]);
    w.y = pack2_bf16(v[2], v[3]);
    w.z = pack2_bf16(v[4], v[5]);
    w.w = pack2_bf16(v[6], v[7]);

    // xt element offset: np*16 + 8h  ->  ushort index t*8 (16 B per thread)
    *(uint4*)(xt + (size_t)t * 8) = w;
}

// ---------------------------------------------------------------------------
// Kernel 2: gather + max from xt (N,P,B) bf16 — b-half split version.
// Thread t: h = t&1 (b = 8h..8h+7), p = (t>>1)&63, m = t>>7.
//   - 9 indices read per thread (dense 36 B/lane streams)
//   - 9 independent 16 B gathers; lane pairs share a 32 B chunk/line
//   - 8 output stores, each two dense 128 B segments, nontemporal so the
//     output doesn't evict xt from L3.
// 2048 blocks -> up to 32 waves/CU for latency hiding.
// ---------------------------------------------------------------------------
__global__ __launch_bounds__(256) void gather_max_bf16_h(
    const unsigned short* __restrict__ xt, const int* __restrict__ lrf,
    float* __restrict__ out, int M, int N) {
    int t = blockIdx.x * 256 + threadIdx.x;     // over M*64*2
    int h = t & 1;
    int p = (t >> 1) & 63;
    int m = t >> 7;
    if (m >= M) return;

    const int* ip = lrf + ((size_t)m * P_DIM + p) * L_DIM;
    int idx[L_DIM];
    #pragma unroll
    for (int l = 0; l < L_DIM; ++l) idx[l] = ip[l];

    float mx[8];
    #pragma unroll
    for (int b = 0; b < 8; ++b) mx[b] = -INFINITY;

    #pragma unroll
    for (int l = 0; l < L_DIM; ++l) {
        const uint4* src = (const uint4*)(xt +
            ((size_t)idx[l] * P_DIM + p) * B_DIM + 8 * h);
        uint4 a = *src;
        unsigned int w[4] = {a.x, a.y, a.z, a.w};
        #pragma unroll
        for (int k = 0; k < 4; ++k) {
            float flo = __uint_as_float(w[k] << 16);          // low bf16 (exact)
            float fhi = __uint_as_float(w[k] & 0xFFFF0000u);  // high bf16 (exact)
            mx[2 * k]     = fmaxf(mx[2 * k],     flo);
            mx[2 * k + 1] = fmaxf(mx[2 * k + 1], fhi);
        }
    }

    size_t ob = (size_t)(8 * h) * M * P_DIM + (size_t)m * P_DIM + p;
    #pragma unroll
    for (int j = 0; j < 8; ++j)
        __builtin_nontemporal_store(mx[j], out + ob + (size_t)j * M * P_DIM);
}

// ---------------------------------------------------------------------------
// Fallback: direct gather from x (B,N,P) f32 if workspace is too small.
// ---------------------------------------------------------------------------
__global__ __launch_bounds__(256) void gather_max_direct(
    const float* __restrict__ x, const int* __restrict__ lrf,
    float* __restrict__ out, int M, int N) {
    int t = blockIdx.x * 256 + threadIdx.x;
    int m = t >> 6;
    int p = t & 63;
    if (m >= M) return;

    const int* ip = lrf + ((size_t)m * P_DIM + p) * L_DIM;
    int idx[L_DIM];
    #pragma unroll
    for (int l = 0; l < L_DIM; ++l) idx[l] = ip[l];

    float mx[16];
    #pragma unroll
    for (int b = 0; b < 16; ++b) mx[b] = -INFINITY;

    #pragma unroll
    for (int l = 0; l < L_DIM; ++l) {
        const float* col = x + (size_t)idx[l] * P_DIM + p;
        #pragma unroll
        for (int b = 0; b < 16; ++b)
            mx[b] = fmaxf(mx[b], col[(size_t)b * N * P_DIM]);
    }

    #pragma unroll
    for (int b = 0; b < 16; ++b)
        out[(size_t)b * M * P_DIM + (size_t)m * P_DIM + p] = mx[b];
}

extern "C" void kernel_launch(void* const* d_in, const int* in_sizes, int n_in,
                              void* d_out, int out_size, void* d_ws, size_t ws_size,
                              hipStream_t stream) {
    const float* x   = (const float*)d_in[0];
    const int*   lrf = (const int*)d_in[1];
    float*       out = (float*)d_out;

    const int N = in_sizes[0] / (B_DIM * P_DIM);   // 65536
    const int M = in_sizes[1] / (P_DIM * L_DIM);   // 4096

    const size_t xt_bytes = (size_t)N * P_DIM * B_DIM * sizeof(unsigned short); // 128 MiB

    if (ws_size >= xt_bytes) {
        unsigned short* xt = (unsigned short*)d_ws;
        {
            int threads = N * P_DIM * 2;           // 8.4M
            int blocks = (threads + 255) / 256;    // 32768
            transpose_pack_bf16<<<blocks, 256, 0, stream>>>(x, xt, N);
        }
        {
            int threads = M * P_DIM * 2;           // 512K
            int blocks = (threads + 255) / 256;    // 2048
            gather_max_bf16_h<<<blocks, 256, 0, stream>>>(xt, lrf, out, M, N);
        }
    } else {
        int threads = M * P_DIM;
        int blocks = (threads + 255) / 256;
        gather_max_direct<<<blocks, 256, 0, stream>>>(x, lrf, out, M, N);
    }
}